// Round 12
// baseline (6284.536 us; speedup 1.0000x reference)
//
#include <hip/hip_runtime.h>
#include <hip/hip_bf16.h>

constexpr int Nn = 4096;
constexpr float EPSf = 1e-5f;

__device__ __forceinline__ float lrelu(float v){ return v >= 0.f ? v : 0.2f * v; }

// ---------------- top-k under total order (score desc, index asc) ----------------
__device__ __forceinline__ void topk_ins(float (&tv)[20], int (&ti)[20],
                                         float &minv, int &minpos, float s, int m){
#pragma unroll
  for (int i = 0; i < 20; ++i){
    bool sel = (i == minpos);
    tv[i] = sel ? s : tv[i];
    ti[i] = sel ? m : ti[i];
  }
  minv = tv[0]; minpos = 0;
#pragma unroll
  for (int i = 1; i < 20; ++i){
    if (tv[i] < minv){ minv = tv[i]; minpos = i; }
  }
}

// total-order variant: tracks worst element under (value asc, index desc)
__device__ __forceinline__ void topk_ins2(float (&tv)[20], int (&ti)[20],
                                          float &minv, int &mini, int &minpos,
                                          float s, int m){
#pragma unroll
  for (int i = 0; i < 20; ++i){
    bool sel = (i == minpos);
    tv[i] = sel ? s : tv[i];
    ti[i] = sel ? m : ti[i];
  }
  minv = tv[0]; mini = ti[0]; minpos = 0;
#pragma unroll
  for (int i = 1; i < 20; ++i){
    bool worse = (tv[i] < minv) || (tv[i] == minv && ti[i] > mini);
    if (worse){ minv = tv[i]; mini = ti[i]; minpos = i; }
  }
}

// ---------------- KNN C=3: tiled full scan, index order (tie-safe) ----------------
__global__ __launch_bounds__(128)
void knn1_t(const float* __restrict__ xin, int* __restrict__ idxout)
{
  __shared__ float4 tile[128];
  const int tid = threadIdx.x;
  const int row = blockIdx.x * 128 + tid;   // 256 blocks
  const int mbase = (row >> 12) * Nn;

  const float c0 = xin[row*3+0], c1 = xin[row*3+1], c2 = xin[row*3+2];

  float tv[20]; int ti[20];
#pragma unroll
  for (int i = 0; i < 20; ++i){ tv[i] = -3.4e38f; ti[i] = 0; }
  float minv = -3.4e38f; int minpos = 0;

  for (int t0 = 0; t0 < Nn; t0 += 128){
    int m = t0 + tid;
    float a0 = xin[(mbase + m)*3 + 0];
    float a1 = xin[(mbase + m)*3 + 1];
    float a2 = xin[(mbase + m)*3 + 2];
    tile[tid] = make_float4(a0, a1, a2, a0*a0 + a1*a1 + a2*a2);
    __syncthreads();
#pragma unroll 1
    for (int ml = 0; ml < 128; ++ml){
      float4 v = tile[ml];
      float score = 2.f * (v.x*c0 + v.y*c1 + v.z*c2) - v.w;
      if (score > minv) topk_ins(tv, ti, minv, minpos, score, mbase + t0 + ml);
    }
    __syncthreads();
  }
#pragma unroll
  for (int i = 0; i < 20; ++i) idxout[row * 20 + i] = ti[i];
}

// ---------------- KNN C=64: 4-way candidate split, total-order top-k, LDS merge ----------------
// __launch_bounds__(256,3): VGPR cap ~170 (needs ~130 live: creg64+tv20+ti20+temps).
// (256,4) forced VGPR=64 -> tv/ti/creg spilled to scratch (R10: FETCH 41MB vs 8MB algorithmic).
__global__ __launch_bounds__(256, 3)
void knn64_s(const float* __restrict__ xin, int* __restrict__ idxout)
{
  __shared__ float smem[8320];     // scan: tile[8192] + txx[128]; merge: mv[3840]+mi[3840]
  float* txx = smem + 8192;
  const int tid = threadIdx.x;
  const int w    = tid >> 6;       // split 0..3
  const int lane = tid & 63;       // local row
  const int row  = blockIdx.x * 64 + lane;   // 512 blocks, same batch per block
  const int mbase = (row >> 12) * Nn;

  float creg[64];
  {
    const float4* src = (const float4*)(xin + (size_t)row * 64);
#pragma unroll
    for (int q = 0; q < 16; ++q) *(float4*)&creg[4*q] = src[q];
  }

  float tv[20]; int ti[20];
#pragma unroll
  for (int i = 0; i < 20; ++i){ tv[i] = -3.4e38f; ti[i] = 0; }
  float minv = -3.4e38f; int mini = 0; int minpos = 0;

  for (int t0 = 0; t0 < Nn; t0 += 128){
    // stage 128 candidate rows (2048 float4, 8 per thread)
    {
      const float4* src = (const float4*)(xin + (size_t)(mbase + t0) * 64);
      float4* dst = (float4*)smem;
#pragma unroll
      for (int it = 0; it < 8; ++it) dst[it * 256 + tid] = src[it * 256 + tid];
    }
    __syncthreads();
    // norms (rotated reads: 2-way bank alias only)
    if (tid < 128){
      const float4* trow = (const float4*)(smem + tid * 64);
      float s0 = 0.f, s1 = 0.f;
#pragma unroll
      for (int j = 0; j < 16; j += 2){
        float4 a = trow[(j + tid) & 15];
        float4 b = trow[(j + 1 + tid) & 15];
        s0 += a.x*a.x + a.y*a.y + a.z*a.z + a.w*a.w;
        s1 += b.x*b.x + b.y*b.y + b.z*b.z + b.w*b.w;
      }
      txx[tid] = s0 + s1;
    }
    __syncthreads();
    // scan this wave's 32 candidates (wave-uniform addr -> LDS broadcast)
#pragma unroll 1
    for (int j = 0; j < 32; ++j){
      int ml = (j << 2) | w;
      const float4* trow = (const float4*)(smem + ml * 64);
      float d0 = 0.f, d1 = 0.f, d2 = 0.f, d3 = 0.f;
#pragma unroll
      for (int q = 0; q < 16; q += 4){
        float4 v0 = trow[q+0], v1 = trow[q+1], v2 = trow[q+2], v3 = trow[q+3];
        d0 += creg[4*q+ 0]*v0.x + creg[4*q+ 1]*v0.y + creg[4*q+ 2]*v0.z + creg[4*q+ 3]*v0.w;
        d1 += creg[4*q+ 4]*v1.x + creg[4*q+ 5]*v1.y + creg[4*q+ 6]*v1.z + creg[4*q+ 7]*v1.w;
        d2 += creg[4*q+ 8]*v2.x + creg[4*q+ 9]*v2.y + creg[4*q+10]*v2.z + creg[4*q+11]*v2.w;
        d3 += creg[4*q+12]*v3.x + creg[4*q+13]*v3.y + creg[4*q+14]*v3.z + creg[4*q+15]*v3.w;
      }
      float score = 2.f * ((d0 + d1) + (d2 + d3)) - txx[ml];
      int gm = mbase + t0 + ml;
      if (score > minv || (score == minv && gm < mini))
        topk_ins2(tv, ti, minv, mini, minpos, score, gm);
    }
    __syncthreads();
  }

  // merge: splits 1..3 publish lists (tile region is dead)
  float* mv = smem;                  // [3][64][20]
  int*   mi = (int*)(smem + 3840);
  if (w > 0){
#pragma unroll
    for (int i = 0; i < 20; ++i){
      mv[((w-1)*64 + lane)*20 + i] = tv[i];
      mi[((w-1)*64 + lane)*20 + i] = ti[i];
    }
  }
  __syncthreads();
  if (w == 0){
#pragma unroll 1
    for (int ss = 0; ss < 3; ++ss){
#pragma unroll 1
      for (int i = 0; i < 20; ++i){
        float v = mv[(ss*64 + lane)*20 + i];
        int   m = mi[(ss*64 + lane)*20 + i];
        if (v > minv || (v == minv && m < mini))
          topk_ins2(tv, ti, minv, mini, minpos, v, m);
      }
    }
#pragma unroll
    for (int i = 0; i < 20; ++i) idxout[row * 20 + i] = ti[i];
  }
}

// ---------------- stage 1: (3) -> edge6 -> 64 -> 64, max over k (4 waves x 8 rows) ----------------
__global__ __launch_bounds__(256)
void edge_first(const float* __restrict__ x, const int* __restrict__ idx,
                const float* __restrict__ W1, const float* __restrict__ bn1,
                const float* __restrict__ W2, const float* __restrict__ bn2,
                float* __restrict__ x1)
{
  const int tid = threadIdx.x;
  const int o = tid & 63;
  const int w = tid >> 6;
  float w1r[6];
#pragma unroll
  for (int j = 0; j < 6; ++j) w1r[j] = W1[o * 6 + j];
  float S1 = bn1[o] * rsqrtf(bn1[192 + o] + EPSf);
  float B1 = bn1[64 + o] - bn1[128 + o] * S1;
  float w2r[64];
#pragma unroll
  for (int q = 0; q < 16; ++q) *(float4*)&w2r[4*q] = *(const float4*)&W2[o * 64 + 4*q];
  float S2 = bn2[o] * rsqrtf(bn2[192 + o] + EPSf);
  float B2 = bn2[64 + o] - bn2[128 + o] * S2;

  __shared__ float h1buf[4][64];
  const int pbase = blockIdx.x * 32 + w * 8;   // 1024 blocks
  for (int i = 0; i < 8; ++i){
    int row = pbase + i;
    float c0 = x[row*3+0], c1 = x[row*3+1], c2 = x[row*3+2];
    float acc = -3.4e38f;
    const int* ip = idx + row * 20;
    for (int k = 0; k < 20; ++k){
      int mg = ip[k];
      float t = w1r[0]*(x[mg*3+0]-c0) + w1r[1]*(x[mg*3+1]-c1) + w1r[2]*(x[mg*3+2]-c2)
              + w1r[3]*c0 + w1r[4]*c1 + w1r[5]*c2;
      h1buf[w][o] = lrelu(t * S1 + B1);
      __syncthreads();
      float t2 = 0.f;
#pragma unroll
      for (int q = 0; q < 16; ++q){
        float4 hv = *(float4*)&h1buf[w][4*q];
        t2 += w2r[4*q]*hv.x + w2r[4*q+1]*hv.y + w2r[4*q+2]*hv.z + w2r[4*q+3]*hv.w;
      }
      __syncthreads();
      acc = fmaxf(acc, lrelu(t2 * S2 + B2));
    }
    x1[(size_t)row * 64 + o] = acc;
  }
}

// ---------------- stage 2: (64) -> edge128 -> 64 -> 64, max over k ----------------
__global__ __launch_bounds__(256, 2)
void edge_mid(const float* __restrict__ xin, const int* __restrict__ idx,
              const float* __restrict__ Wa, const float* __restrict__ bna,
              const float* __restrict__ Wb, const float* __restrict__ bnb,
              float* __restrict__ xout)
{
  const int tid = threadIdx.x;
  const int o = tid & 63;
  const int w = tid >> 6;
  float war[128];
#pragma unroll
  for (int q = 0; q < 32; ++q) *(float4*)&war[4*q] = *(const float4*)&Wa[o * 128 + 4*q];
  float Sa = bna[o] * rsqrtf(bna[192 + o] + EPSf);
  float Ba = bna[64 + o] - bna[128 + o] * Sa;
  float wbr[64];
#pragma unroll
  for (int q = 0; q < 16; ++q) *(float4*)&wbr[4*q] = *(const float4*)&Wb[o * 64 + 4*q];
  float Sb = bnb[o] * rsqrtf(bnb[192 + o] + EPSf);
  float Bb = bnb[64 + o] - bnb[128 + o] * Sb;

  __shared__ float fbuf[4][128];
  __shared__ float hbuf[4][64];
  const int pbase = blockIdx.x * 32 + w * 8;
  for (int i = 0; i < 8; ++i){
    int row = pbase + i;
    float co = xin[(size_t)row * 64 + o];
    fbuf[w][64 + o] = co;
    float acc = -3.4e38f;
    const int* ip = idx + row * 20;
    for (int k = 0; k < 20; ++k){
      int mg = ip[k];
      fbuf[w][o] = xin[(size_t)mg * 64 + o] - co;
      __syncthreads();
      float t = 0.f;
#pragma unroll
      for (int q = 0; q < 32; ++q){
        float4 fv = *(float4*)&fbuf[w][4*q];
        t += war[4*q]*fv.x + war[4*q+1]*fv.y + war[4*q+2]*fv.z + war[4*q+3]*fv.w;
      }
      hbuf[w][o] = lrelu(t * Sa + Ba);
      __syncthreads();
      float t2 = 0.f;
#pragma unroll
      for (int q = 0; q < 16; ++q){
        float4 hv = *(float4*)&hbuf[w][4*q];
        t2 += wbr[4*q]*hv.x + wbr[4*q+1]*hv.y + wbr[4*q+2]*hv.z + wbr[4*q+3]*hv.w;
      }
      acc = fmaxf(acc, lrelu(t2 * Sb + Bb));
    }
    xout[(size_t)row * 64 + o] = acc;
  }
}

// ---------------- stage 3: (64) -> edge128 -> 64, max over k ----------------
__global__ __launch_bounds__(256, 2)
void edge_last(const float* __restrict__ xin, const int* __restrict__ idx,
               const float* __restrict__ Wa, const float* __restrict__ bna,
               float* __restrict__ xout)
{
  const int tid = threadIdx.x;
  const int o = tid & 63;
  const int w = tid >> 6;
  float war[128];
#pragma unroll
  for (int q = 0; q < 32; ++q) *(float4*)&war[4*q] = *(const float4*)&Wa[o * 128 + 4*q];
  float Sa = bna[o] * rsqrtf(bna[192 + o] + EPSf);
  float Ba = bna[64 + o] - bna[128 + o] * Sa;

  __shared__ float fbuf[4][128];
  const int pbase = blockIdx.x * 32 + w * 8;
  for (int i = 0; i < 8; ++i){
    int row = pbase + i;
    float co = xin[(size_t)row * 64 + o];
    fbuf[w][64 + o] = co;
    float acc = -3.4e38f;
    const int* ip = idx + row * 20;
    for (int k = 0; k < 20; ++k){
      int mg = ip[k];
      fbuf[w][o] = xin[(size_t)mg * 64 + o] - co;
      __syncthreads();
      float t = 0.f;
#pragma unroll
      for (int q = 0; q < 32; ++q){
        float4 fv = *(float4*)&fbuf[w][4*q];
        t += war[4*q]*fv.x + war[4*q+1]*fv.y + war[4*q+2]*fv.z + war[4*q+3]*fv.w;
      }
      __syncthreads();
      acc = fmaxf(acc, lrelu(t * Sa + Ba));
    }
    xout[(size_t)row * 64 + o] = acc;
  }
}

// ---------------- W6 (192->1024) + BN + LReLU + mean partials ----------------
__global__ __launch_bounds__(256, 2)
void vf_mean(const float* __restrict__ x1, const float* __restrict__ x2,
             const float* __restrict__ x3, const float* __restrict__ W6,
             const float* __restrict__ bn6, float* __restrict__ gsum)
{
  const int tid = threadIdx.x;
  const int bid = blockIdx.x;                 // 512 blocks
  const int oc = bid & 3, nch = (bid >> 2) & 15, b = bid >> 6;
  const int o = oc * 256 + tid;
  float wr[192];
#pragma unroll
  for (int q = 0; q < 48; ++q) *(float4*)&wr[4*q] = *(const float4*)&W6[o * 192 + 4*q];
  float S = bn6[o] * rsqrtf(bn6[3*1024 + o] + EPSf);
  float Bn = bn6[1024 + o] - bn6[2*1024 + o] * S;

  __shared__ float cbuf[8 * 192];
  float local = 0.f;
  const int nbase = b * Nn + nch * 256;
  for (int p0 = 0; p0 < 256; p0 += 8){
#pragma unroll
    for (int it = 0; it < 6; ++it){
      int i = it * 256 + tid;
      int p = i / 192, j = i - p * 192;
      int row = nbase + p0 + p;
      float v = (j < 64) ? x1[(size_t)row*64 + j]
              : (j < 128) ? x2[(size_t)row*64 + j - 64]
              : x3[(size_t)row*64 + j - 128];
      cbuf[p * 192 + j] = v;
    }
    __syncthreads();
#pragma unroll 1
    for (int p = 0; p < 8; ++p){
      float t = 0.f;
#pragma unroll
      for (int q = 0; q < 48; ++q){
        float4 fv = *(float4*)&cbuf[p * 192 + 4*q];
        t += wr[4*q]*fv.x + wr[4*q+1]*fv.y + wr[4*q+2]*fv.z + wr[4*q+3]*fv.w;
      }
      local += lrelu(t * S + Bn);
    }
    __syncthreads();
  }
  atomicAdd(&gsum[b * 1024 + o], local);
}

// ---------------- finalize g: mean, fp32 out ----------------
__global__ void g_final(float* __restrict__ g, float* __restrict__ gout)
{
  int i = blockIdx.x * 256 + threadIdx.x;   // 32 blocks -> 8192
  float v = g[i] * (1.f / 4096.f);
  g[i] = v;
  gout[i] = v;
}

// ---------------- gb7[b][o] = W7[o, 0:1024] . g[b] ----------------
__global__ void gbias7_k(const float* __restrict__ g, const float* __restrict__ W7,
                         float* __restrict__ gb7)
{
  const int tid = threadIdx.x;
  const int b = blockIdx.x >> 1, half = blockIdx.x & 1;   // 16 blocks
  const int o = half * 256 + tid;
  __shared__ float gs[1024];
#pragma unroll
  for (int it = 0; it < 4; ++it) gs[it * 256 + tid] = g[b * 1024 + it * 256 + tid];
  __syncthreads();
  float t = 0.f;
  const float4* wrow = (const float4*)&W7[(size_t)o * 1216];
#pragma unroll 8
  for (int q = 0; q < 256; ++q){
    float4 wv = wrow[q];
    float4 gv = *(float4*)&gs[4*q];
    t += wv.x*gv.x + wv.y*gv.y + wv.z*gv.z + wv.w*gv.w;
  }
  gb7[b * 512 + o] = t;
}

// ---------------- transpose W7x (cols 1024..1215) and W8 ----------------
__global__ void transpose_k(const float* __restrict__ W7, const float* __restrict__ W8,
                            float* __restrict__ w7xt, float* __restrict__ w8t)
{
  int i = blockIdx.x * 256 + threadIdx.x;    // 896 blocks -> 229376
  if (i < 98304){
    int j = i >> 9, o = i & 511;
    w7xt[i] = W7[(size_t)o * 1216 + 1024 + j];
  } else {
    int i2 = i - 98304;
    int j = i2 >> 8, o = i2 & 255;
    w8t[i2] = W8[o * 512 + j];
  }
}

// ---------------- final per-point MLP: 192(+gbias)->512->256->3 ----------------
__global__ __launch_bounds__(256, 2)
void mlp_final(const float* __restrict__ x1, const float* __restrict__ x2,
               const float* __restrict__ x3, const float* __restrict__ w7xt,
               const float* __restrict__ gb7, const float* __restrict__ bn7,
               const float* __restrict__ w8t, const float* __restrict__ bn8,
               const float* __restrict__ W9, float* __restrict__ out)
{
  const int tid = threadIdx.x;
  const int row0 = blockIdx.x * 16;     // 2048 blocks
  const int b = row0 >> 12;
  __shared__ float A[256 * 20];    // cat [192][20], later h8 [256][20]
  __shared__ float H7[512 * 20];

#pragma unroll
  for (int it = 0; it < 12; ++it){
    int i = it * 256 + tid;
    int part = i >> 10, rem = i & 1023;
    int p = rem >> 6, o = rem & 63;
    const float* src = part == 0 ? x1 : part == 1 ? x2 : x3;
    A[(part * 64 + o) * 20 + p] = src[(size_t)(row0 + p) * 64 + o];
  }
  __syncthreads();

  const int o0 = tid, o1 = 256 + tid;
  float S0 = bn7[o0] * rsqrtf(bn7[3*512 + o0] + EPSf);
  float Bs0 = gb7[b*512 + o0] * S0 + bn7[512 + o0] - bn7[2*512 + o0] * S0;
  float S1 = bn7[o1] * rsqrtf(bn7[3*512 + o1] + EPSf);
  float Bs1 = gb7[b*512 + o1] * S1 + bn7[512 + o1] - bn7[2*512 + o1] * S1;
  float acc0[16], acc1[16];
#pragma unroll
  for (int p = 0; p < 16; ++p){ acc0[p] = 0.f; acc1[p] = 0.f; }
#pragma unroll 2
  for (int j = 0; j < 192; ++j){
    float w0 = w7xt[j * 512 + o0];
    float w1 = w7xt[j * 512 + o1];
#pragma unroll
    for (int q = 0; q < 4; ++q){
      float4 f = *(float4*)&A[j * 20 + 4*q];
      acc0[4*q+0] += w0 * f.x; acc0[4*q+1] += w0 * f.y; acc0[4*q+2] += w0 * f.z; acc0[4*q+3] += w0 * f.w;
      acc1[4*q+0] += w1 * f.x; acc1[4*q+1] += w1 * f.y; acc1[4*q+2] += w1 * f.z; acc1[4*q+3] += w1 * f.w;
    }
  }
#pragma unroll
  for (int p = 0; p < 16; ++p){
    H7[o0 * 20 + p] = lrelu(acc0[p] * S0 + Bs0);
    H7[o1 * 20 + p] = lrelu(acc1[p] * S1 + Bs1);
  }
  __syncthreads();

  float S8 = bn8[tid] * rsqrtf(bn8[3*256 + tid] + EPSf);
  float B8 = bn8[256 + tid] - bn8[2*256 + tid] * S8;
  float acc8[16];
#pragma unroll
  for (int p = 0; p < 16; ++p) acc8[p] = 0.f;
#pragma unroll 2
  for (int j = 0; j < 512; ++j){
    float wv = w8t[j * 256 + tid];
#pragma unroll
    for (int q = 0; q < 4; ++q){
      float4 h = *(float4*)&H7[j * 20 + 4*q];
      acc8[4*q+0] += wv * h.x; acc8[4*q+1] += wv * h.y; acc8[4*q+2] += wv * h.z; acc8[4*q+3] += wv * h.w;
    }
  }
  __syncthreads();
#pragma unroll
  for (int p = 0; p < 16; ++p) A[tid * 20 + p] = lrelu(acc8[p] * S8 + B8);
  __syncthreads();

  if (tid < 192){
    int c = tid >> 6, j0 = tid & 63;
    float w9r[4];
#pragma unroll
    for (int q = 0; q < 4; ++q) w9r[q] = W9[c * 256 + j0 + 64*q];
#pragma unroll 1
    for (int p = 0; p < 16; ++p){
      float s = 0.f;
#pragma unroll
      for (int q = 0; q < 4; ++q) s += w9r[q] * A[(j0 + 64*q) * 20 + p];
#pragma unroll
      for (int off = 32; off; off >>= 1) s += __shfl_down(s, off, 64);
      if (j0 == 0) out[(size_t)(row0 + p) * 3 + c] = s;
    }
  }
}

__global__ void sentinel_k(float* __restrict__ o, float val){
  int i = blockIdx.x*256 + threadIdx.x;
  if (i < 106496) o[i] = val;
}

extern "C" void kernel_launch(void* const* d_in, const int* in_sizes, int n_in,
                              void* d_out, int out_size, void* d_ws, size_t ws_size,
                              hipStream_t stream) {
  const float* x  = (const float*)d_in[0];
  const float* W1 = (const float*)d_in[1];
  const float* W2 = (const float*)d_in[2];
  const float* W3 = (const float*)d_in[3];
  const float* W4 = (const float*)d_in[4];
  const float* W5 = (const float*)d_in[5];
  const float* W6 = (const float*)d_in[6];
  const float* W7 = (const float*)d_in[7];
  const float* W8 = (const float*)d_in[8];
  const float* W9 = (const float*)d_in[9];
  const float* bn1 = (const float*)d_in[10];
  const float* bn2 = (const float*)d_in[11];
  const float* bn3 = (const float*)d_in[12];
  const float* bn4 = (const float*)d_in[13];
  const float* bn5 = (const float*)d_in[14];
  const float* bn6 = (const float*)d_in[15];
  const float* bn7 = (const float*)d_in[16];
  const float* bn8 = (const float*)d_in[17];

  float* out_g = (float*)d_out;        // g: 8*1024 fp32
  float* out_o = out_g + 8192;         // out: 8*4096*3 fp32

  bool ok_sizes = (n_in == 18) && in_sizes[0]==98304 && out_size == 106496;
  if (!ok_sizes){ sentinel_k<<<416, 256, 0, stream>>>((float*)d_out, 999.0f); return; }

  float* wsf  = (float*)d_ws;
  float* x1   = wsf;                        // 2,097,152 f
  float* x2   = x1 + 2097152;               // 2,097,152 f
  float* x3   = x2 + 2097152;               // 2,097,152 f
  float* gbuf = x3 + 2097152;               // 8,192 f
  int*   idxb = (int*)(gbuf + 8192);        // 655,360 i
  float* gb7  = (float*)idxb;               // overlay after edge_last
  float* w7xt = gb7 + 4096;
  float* w8t  = w7xt + 98304;
  const size_t NEED = (size_t)(2097152*3 + 8192 + 655360) * 4;
  if (ws_size < NEED){ sentinel_k<<<416, 256, 0, stream>>>((float*)d_out, 12345.0f); return; }

  hipMemsetAsync(gbuf, 0, 8192 * sizeof(float), stream);

  knn1_t<<<256, 128, 0, stream>>>(x, idxb);
  edge_first<<<1024, 256, 0, stream>>>(x, idxb, W1, bn1, W2, bn2, x1);
  knn64_s<<<512, 256, 0, stream>>>(x1, idxb);
  edge_mid<<<1024, 256, 0, stream>>>(x1, idxb, W3, bn3, W4, bn4, x2);
  knn64_s<<<512, 256, 0, stream>>>(x2, idxb);
  edge_last<<<1024, 256, 0, stream>>>(x2, idxb, W5, bn5, x3);
  transpose_k<<<896, 256, 0, stream>>>(W7, W8, w7xt, w8t);
  vf_mean<<<512, 256, 0, stream>>>(x1, x2, x3, W6, bn6, gbuf);
  g_final<<<32, 256, 0, stream>>>(gbuf, out_g);
  gbias7_k<<<16, 256, 0, stream>>>(gbuf, W7, gb7);
  mlp_final<<<2048, 256, 0, stream>>>(x1, x2, x3, w7xt, gb7, bn7, w8t, bn8, W9, out_o);
}

// Round 13
// 5238.590 us; speedup vs baseline: 1.1997x; 1.1997x over previous
//
#include <hip/hip_runtime.h>
#include <hip/hip_bf16.h>

constexpr int Nn = 4096;
constexpr float EPSf = 1e-5f;
constexpr int KBUF = 12;     // per-lane buffered candidates

__device__ __forceinline__ float lrelu(float v){ return v >= 0.f ? v : 0.2f * v; }

// ---------------- top-k insertion (simple, index-order streams) ----------------
__device__ __forceinline__ void topk_ins(float (&tv)[20], int (&ti)[20],
                                         float &minv, int &minpos, float s, int m){
#pragma unroll
  for (int i = 0; i < 20; ++i){
    bool sel = (i == minpos);
    tv[i] = sel ? s : tv[i];
    ti[i] = sel ? m : ti[i];
  }
  minv = tv[0]; minpos = 0;
#pragma unroll
  for (int i = 1; i < 20; ++i){
    if (tv[i] < minv){ minv = tv[i]; minpos = i; }
  }
}

// total-order variant: tracks worst element under (value asc, index desc)
__device__ __forceinline__ void topk_ins2(float (&tv)[20], int (&ti)[20],
                                          float &minv, int &mini, int &minpos,
                                          float s, int m){
#pragma unroll
  for (int i = 0; i < 20; ++i){
    bool sel = (i == minpos);
    tv[i] = sel ? s : tv[i];
    ti[i] = sel ? m : ti[i];
  }
  minv = tv[0]; mini = ti[0]; minpos = 0;
#pragma unroll
  for (int i = 1; i < 20; ++i){
    bool worse = (tv[i] < minv) || (tv[i] == minv && ti[i] > mini);
    if (worse){ minv = tv[i]; mini = ti[i]; minpos = i; }
  }
}

// ---------------- KNN C=3: tiled full scan, index order (tie-safe) ----------------
__global__ __launch_bounds__(128)
void knn1_t(const float* __restrict__ xin, int* __restrict__ idxout)
{
  __shared__ float4 tile[128];
  const int tid = threadIdx.x;
  const int row = blockIdx.x * 128 + tid;   // 256 blocks
  const int mbase = (row >> 12) * Nn;

  const float c0 = xin[row*3+0], c1 = xin[row*3+1], c2 = xin[row*3+2];

  float tv[20]; int ti[20];
#pragma unroll
  for (int i = 0; i < 20; ++i){ tv[i] = -3.4e38f; ti[i] = 0; }
  float minv = -3.4e38f; int minpos = 0;

  for (int t0 = 0; t0 < Nn; t0 += 128){
    int m = t0 + tid;
    float a0 = xin[(mbase + m)*3 + 0];
    float a1 = xin[(mbase + m)*3 + 1];
    float a2 = xin[(mbase + m)*3 + 2];
    tile[tid] = make_float4(a0, a1, a2, a0*a0 + a1*a1 + a2*a2);
    __syncthreads();
#pragma unroll 1
    for (int ml = 0; ml < 128; ++ml){
      float4 v = tile[ml];
      float score = 2.f * (v.x*c0 + v.y*c1 + v.z*c2) - v.w;
      if (score > minv) topk_ins(tv, ti, minv, minpos, score, mbase + t0 + ml);
    }
    __syncthreads();
  }
#pragma unroll
  for (int i = 0; i < 20; ++i) idxout[row * 20 + i] = ti[i];
}

// ---------------- KNN C=64: 4-way split + per-lane LDS candidate buffering ----------------
// R12 model: top-20 insertion body (~160 instr) triggered at wave level on ~90% of
// 1024 steps = 2/3 of VALU work. Buffer passing candidates per lane (push ~4 instr),
// run the body only on drain (~99-165 execs). Stale accepts re-tested at drain;
// rejections are final (minv monotone) -> exact.
__global__ __launch_bounds__(256, 3)
void knn64_s(const float* __restrict__ xin, int* __restrict__ idxout)
{
  __shared__ float tile[8192];        // 128 rows x 64
  __shared__ float txx[128];
  __shared__ float lbufs[256 * 25];   // per-lane: 12 x (score,idx) + 1 pad word
  const int tid = threadIdx.x;
  const int w    = tid >> 6;          // split 0..3
  const int lane = tid & 63;          // local row
  const int row  = blockIdx.x * 64 + lane;   // 512 blocks
  const int mbase = (row >> 12) * Nn;
  float* lbuf = lbufs + tid * 25;

  float creg[64];
  {
    const float4* src = (const float4*)(xin + (size_t)row * 64);
#pragma unroll
    for (int q = 0; q < 16; ++q) *(float4*)&creg[4*q] = src[q];
  }

  float tv[20]; int ti[20];
#pragma unroll
  for (int i = 0; i < 20; ++i){ tv[i] = -3.4e38f; ti[i] = 0; }
  float minv = -3.4e38f; int mini = 0; int minpos = 0;
  int cnt = 0;

  for (int t0 = 0; t0 < Nn; t0 += 128){
    {
      const float4* src = (const float4*)(xin + (size_t)(mbase + t0) * 64);
      float4* dst = (float4*)tile;
#pragma unroll
      for (int it = 0; it < 8; ++it) dst[it * 256 + tid] = src[it * 256 + tid];
    }
    __syncthreads();
    if (tid < 128){
      const float4* trow = (const float4*)(tile + tid * 64);
      float s0 = 0.f, s1 = 0.f;
#pragma unroll
      for (int j = 0; j < 16; j += 2){
        float4 a = trow[(j + tid) & 15];
        float4 b = trow[(j + 1 + tid) & 15];
        s0 += a.x*a.x + a.y*a.y + a.z*a.z + a.w*a.w;
        s1 += b.x*b.x + b.y*b.y + b.z*b.z + b.w*b.w;
      }
      txx[tid] = s0 + s1;
    }
    __syncthreads();
#pragma unroll 1
    for (int j = 0; j < 32; ++j){
      int ml = (j << 2) | w;
      const float4* trow = (const float4*)(tile + ml * 64);
      float d0 = 0.f, d1 = 0.f, d2 = 0.f, d3 = 0.f;
#pragma unroll
      for (int q = 0; q < 16; q += 4){
        float4 v0 = trow[q+0], v1 = trow[q+1], v2 = trow[q+2], v3 = trow[q+3];
        d0 += creg[4*q+ 0]*v0.x + creg[4*q+ 1]*v0.y + creg[4*q+ 2]*v0.z + creg[4*q+ 3]*v0.w;
        d1 += creg[4*q+ 4]*v1.x + creg[4*q+ 5]*v1.y + creg[4*q+ 6]*v1.z + creg[4*q+ 7]*v1.w;
        d2 += creg[4*q+ 8]*v2.x + creg[4*q+ 9]*v2.y + creg[4*q+10]*v2.z + creg[4*q+11]*v2.w;
        d3 += creg[4*q+12]*v3.x + creg[4*q+13]*v3.y + creg[4*q+14]*v3.z + creg[4*q+15]*v3.w;
      }
      float score = 2.f * ((d0 + d1) + (d2 + d3)) - txx[ml];
      int gm = mbase + t0 + ml;
      if (score > minv || (score == minv && gm < mini)){
        lbuf[2*cnt] = score;
        ((int*)lbuf)[2*cnt + 1] = gm;
        ++cnt;
      }
      if (__ballot(cnt >= KBUF)){
        int maxc = cnt;
#pragma unroll
        for (int off = 32; off; off >>= 1){
          int o = __shfl_xor(maxc, off, 64);
          maxc = o > maxc ? o : maxc;
        }
#pragma unroll 1
        for (int e = 0; e < maxc; ++e){
          if (e < cnt){
            float v = lbuf[2*e];
            int   m = ((int*)lbuf)[2*e + 1];
            if (v > minv || (v == minv && m < mini))
              topk_ins2(tv, ti, minv, mini, minpos, v, m);
          }
        }
        cnt = 0;
      }
    }
    __syncthreads();
  }
  // final drain
  {
    int maxc = cnt;
#pragma unroll
    for (int off = 32; off; off >>= 1){
      int o = __shfl_xor(maxc, off, 64);
      maxc = o > maxc ? o : maxc;
    }
#pragma unroll 1
    for (int e = 0; e < maxc; ++e){
      if (e < cnt){
        float v = lbuf[2*e];
        int   m = ((int*)lbuf)[2*e + 1];
        if (v > minv || (v == minv && m < mini))
          topk_ins2(tv, ti, minv, mini, minpos, v, m);
      }
    }
    cnt = 0;
  }

  // merge: splits 1..3 publish lists into the dead tile region
  float* mv = tile;                  // [3][64][20] floats
  int*   mi = (int*)(tile + 3840);
  __syncthreads();
  if (w > 0){
#pragma unroll
    for (int i = 0; i < 20; ++i){
      mv[((w-1)*64 + lane)*20 + i] = tv[i];
      mi[((w-1)*64 + lane)*20 + i] = ti[i];
    }
  }
  __syncthreads();
  if (w == 0){
#pragma unroll 1
    for (int ss = 0; ss < 3; ++ss){
#pragma unroll 1
      for (int i = 0; i < 20; ++i){
        float v = mv[(ss*64 + lane)*20 + i];
        int   m = mi[(ss*64 + lane)*20 + i];
        if (v > minv || (v == minv && m < mini))
          topk_ins2(tv, ti, minv, mini, minpos, v, m);
      }
    }
#pragma unroll
    for (int i = 0; i < 20; ++i) idxout[row * 20 + i] = ti[i];
  }
}

// ---------------- stage 1: (3) -> edge6 -> 64 -> 64, max over k (4 waves x 8 rows) ----------------
__global__ __launch_bounds__(256)
void edge_first(const float* __restrict__ x, const int* __restrict__ idx,
                const float* __restrict__ W1, const float* __restrict__ bn1,
                const float* __restrict__ W2, const float* __restrict__ bn2,
                float* __restrict__ x1)
{
  const int tid = threadIdx.x;
  const int o = tid & 63;
  const int w = tid >> 6;
  float w1r[6];
#pragma unroll
  for (int j = 0; j < 6; ++j) w1r[j] = W1[o * 6 + j];
  float S1 = bn1[o] * rsqrtf(bn1[192 + o] + EPSf);
  float B1 = bn1[64 + o] - bn1[128 + o] * S1;
  float w2r[64];
#pragma unroll
  for (int q = 0; q < 16; ++q) *(float4*)&w2r[4*q] = *(const float4*)&W2[o * 64 + 4*q];
  float S2 = bn2[o] * rsqrtf(bn2[192 + o] + EPSf);
  float B2 = bn2[64 + o] - bn2[128 + o] * S2;

  __shared__ float h1buf[4][64];
  const int pbase = blockIdx.x * 32 + w * 8;   // 1024 blocks
  for (int i = 0; i < 8; ++i){
    int row = pbase + i;
    float c0 = x[row*3+0], c1 = x[row*3+1], c2 = x[row*3+2];
    float acc = -3.4e38f;
    const int* ip = idx + row * 20;
    for (int k = 0; k < 20; ++k){
      int mg = ip[k];
      float t = w1r[0]*(x[mg*3+0]-c0) + w1r[1]*(x[mg*3+1]-c1) + w1r[2]*(x[mg*3+2]-c2)
              + w1r[3]*c0 + w1r[4]*c1 + w1r[5]*c2;
      h1buf[w][o] = lrelu(t * S1 + B1);
      __syncthreads();
      float t2 = 0.f;
#pragma unroll
      for (int q = 0; q < 16; ++q){
        float4 hv = *(float4*)&h1buf[w][4*q];
        t2 += w2r[4*q]*hv.x + w2r[4*q+1]*hv.y + w2r[4*q+2]*hv.z + w2r[4*q+3]*hv.w;
      }
      __syncthreads();
      acc = fmaxf(acc, lrelu(t2 * S2 + B2));
    }
    x1[(size_t)row * 64 + o] = acc;
  }
}

// ---------------- stage 2: (64) -> edge128 -> 64 -> 64, max over k ----------------
__global__ __launch_bounds__(256, 2)
void edge_mid(const float* __restrict__ xin, const int* __restrict__ idx,
              const float* __restrict__ Wa, const float* __restrict__ bna,
              const float* __restrict__ Wb, const float* __restrict__ bnb,
              float* __restrict__ xout)
{
  const int tid = threadIdx.x;
  const int o = tid & 63;
  const int w = tid >> 6;
  float war[128];
#pragma unroll
  for (int q = 0; q < 32; ++q) *(float4*)&war[4*q] = *(const float4*)&Wa[o * 128 + 4*q];
  float Sa = bna[o] * rsqrtf(bna[192 + o] + EPSf);
  float Ba = bna[64 + o] - bna[128 + o] * Sa;
  float wbr[64];
#pragma unroll
  for (int q = 0; q < 16; ++q) *(float4*)&wbr[4*q] = *(const float4*)&Wb[o * 64 + 4*q];
  float Sb = bnb[o] * rsqrtf(bnb[192 + o] + EPSf);
  float Bb = bnb[64 + o] - bnb[128 + o] * Sb;

  __shared__ float fbuf[4][128];
  __shared__ float hbuf[4][64];
  const int pbase = blockIdx.x * 32 + w * 8;
  for (int i = 0; i < 8; ++i){
    int row = pbase + i;
    float co = xin[(size_t)row * 64 + o];
    fbuf[w][64 + o] = co;
    float acc = -3.4e38f;
    const int* ip = idx + row * 20;
    for (int k = 0; k < 20; ++k){
      int mg = ip[k];
      fbuf[w][o] = xin[(size_t)mg * 64 + o] - co;
      __syncthreads();
      float t = 0.f;
#pragma unroll
      for (int q = 0; q < 32; ++q){
        float4 fv = *(float4*)&fbuf[w][4*q];
        t += war[4*q]*fv.x + war[4*q+1]*fv.y + war[4*q+2]*fv.z + war[4*q+3]*fv.w;
      }
      hbuf[w][o] = lrelu(t * Sa + Ba);
      __syncthreads();
      float t2 = 0.f;
#pragma unroll
      for (int q = 0; q < 16; ++q){
        float4 hv = *(float4*)&hbuf[w][4*q];
        t2 += wbr[4*q]*hv.x + wbr[4*q+1]*hv.y + wbr[4*q+2]*hv.z + wbr[4*q+3]*hv.w;
      }
      acc = fmaxf(acc, lrelu(t2 * Sb + Bb));
    }
    xout[(size_t)row * 64 + o] = acc;
  }
}

// ---------------- stage 3: (64) -> edge128 -> 64, max over k ----------------
__global__ __launch_bounds__(256, 2)
void edge_last(const float* __restrict__ xin, const int* __restrict__ idx,
               const float* __restrict__ Wa, const float* __restrict__ bna,
               float* __restrict__ xout)
{
  const int tid = threadIdx.x;
  const int o = tid & 63;
  const int w = tid >> 6;
  float war[128];
#pragma unroll
  for (int q = 0; q < 32; ++q) *(float4*)&war[4*q] = *(const float4*)&Wa[o * 128 + 4*q];
  float Sa = bna[o] * rsqrtf(bna[192 + o] + EPSf);
  float Ba = bna[64 + o] - bna[128 + o] * Sa;

  __shared__ float fbuf[4][128];
  const int pbase = blockIdx.x * 32 + w * 8;
  for (int i = 0; i < 8; ++i){
    int row = pbase + i;
    float co = xin[(size_t)row * 64 + o];
    fbuf[w][64 + o] = co;
    float acc = -3.4e38f;
    const int* ip = idx + row * 20;
    for (int k = 0; k < 20; ++k){
      int mg = ip[k];
      fbuf[w][o] = xin[(size_t)mg * 64 + o] - co;
      __syncthreads();
      float t = 0.f;
#pragma unroll
      for (int q = 0; q < 32; ++q){
        float4 fv = *(float4*)&fbuf[w][4*q];
        t += war[4*q]*fv.x + war[4*q+1]*fv.y + war[4*q+2]*fv.z + war[4*q+3]*fv.w;
      }
      __syncthreads();
      acc = fmaxf(acc, lrelu(t * Sa + Ba));
    }
    xout[(size_t)row * 64 + o] = acc;
  }
}

// ---------------- W6 (192->1024) + BN + LReLU + mean partials ----------------
__global__ __launch_bounds__(256, 2)
void vf_mean(const float* __restrict__ x1, const float* __restrict__ x2,
             const float* __restrict__ x3, const float* __restrict__ W6,
             const float* __restrict__ bn6, float* __restrict__ gsum)
{
  const int tid = threadIdx.x;
  const int bid = blockIdx.x;                 // 512 blocks
  const int oc = bid & 3, nch = (bid >> 2) & 15, b = bid >> 6;
  const int o = oc * 256 + tid;
  float wr[192];
#pragma unroll
  for (int q = 0; q < 48; ++q) *(float4*)&wr[4*q] = *(const float4*)&W6[o * 192 + 4*q];
  float S = bn6[o] * rsqrtf(bn6[3*1024 + o] + EPSf);
  float Bn = bn6[1024 + o] - bn6[2*1024 + o] * S;

  __shared__ float cbuf[8 * 192];
  float local = 0.f;
  const int nbase = b * Nn + nch * 256;
  for (int p0 = 0; p0 < 256; p0 += 8){
#pragma unroll
    for (int it = 0; it < 6; ++it){
      int i = it * 256 + tid;
      int p = i / 192, j = i - p * 192;
      int row = nbase + p0 + p;
      float v = (j < 64) ? x1[(size_t)row*64 + j]
              : (j < 128) ? x2[(size_t)row*64 + j - 64]
              : x3[(size_t)row*64 + j - 128];
      cbuf[p * 192 + j] = v;
    }
    __syncthreads();
#pragma unroll 1
    for (int p = 0; p < 8; ++p){
      float t = 0.f;
#pragma unroll
      for (int q = 0; q < 48; ++q){
        float4 fv = *(float4*)&cbuf[p * 192 + 4*q];
        t += wr[4*q]*fv.x + wr[4*q+1]*fv.y + wr[4*q+2]*fv.z + wr[4*q+3]*fv.w;
      }
      local += lrelu(t * S + Bn);
    }
    __syncthreads();
  }
  atomicAdd(&gsum[b * 1024 + o], local);
}

// ---------------- finalize g: mean, fp32 out ----------------
__global__ void g_final(float* __restrict__ g, float* __restrict__ gout)
{
  int i = blockIdx.x * 256 + threadIdx.x;   // 32 blocks -> 8192
  float v = g[i] * (1.f / 4096.f);
  g[i] = v;
  gout[i] = v;
}

// ---------------- gb7[b][o] = W7[o, 0:1024] . g[b] ----------------
__global__ void gbias7_k(const float* __restrict__ g, const float* __restrict__ W7,
                         float* __restrict__ gb7)
{
  const int tid = threadIdx.x;
  const int b = blockIdx.x >> 1, half = blockIdx.x & 1;   // 16 blocks
  const int o = half * 256 + tid;
  __shared__ float gs[1024];
#pragma unroll
  for (int it = 0; it < 4; ++it) gs[it * 256 + tid] = g[b * 1024 + it * 256 + tid];
  __syncthreads();
  float t = 0.f;
  const float4* wrow = (const float4*)&W7[(size_t)o * 1216];
#pragma unroll 8
  for (int q = 0; q < 256; ++q){
    float4 wv = wrow[q];
    float4 gv = *(float4*)&gs[4*q];
    t += wv.x*gv.x + wv.y*gv.y + wv.z*gv.z + wv.w*gv.w;
  }
  gb7[b * 512 + o] = t;
}

// ---------------- transpose W7x (cols 1024..1215) and W8 ----------------
__global__ void transpose_k(const float* __restrict__ W7, const float* __restrict__ W8,
                            float* __restrict__ w7xt, float* __restrict__ w8t)
{
  int i = blockIdx.x * 256 + threadIdx.x;    // 896 blocks -> 229376
  if (i < 98304){
    int j = i >> 9, o = i & 511;
    w7xt[i] = W7[(size_t)o * 1216 + 1024 + j];
  } else {
    int i2 = i - 98304;
    int j = i2 >> 8, o = i2 & 255;
    w8t[i2] = W8[o * 512 + j];
  }
}

// ---------------- final per-point MLP: 192(+gbias)->512->256->3 ----------------
__global__ __launch_bounds__(256, 2)
void mlp_final(const float* __restrict__ x1, const float* __restrict__ x2,
               const float* __restrict__ x3, const float* __restrict__ w7xt,
               const float* __restrict__ gb7, const float* __restrict__ bn7,
               const float* __restrict__ w8t, const float* __restrict__ bn8,
               const float* __restrict__ W9, float* __restrict__ out)
{
  const int tid = threadIdx.x;
  const int row0 = blockIdx.x * 16;     // 2048 blocks
  const int b = row0 >> 12;
  __shared__ float A[256 * 20];    // cat [192][20], later h8 [256][20]
  __shared__ float H7[512 * 20];

#pragma unroll
  for (int it = 0; it < 12; ++it){
    int i = it * 256 + tid;
    int part = i >> 10, rem = i & 1023;
    int p = rem >> 6, o = rem & 63;
    const float* src = part == 0 ? x1 : part == 1 ? x2 : x3;
    A[(part * 64 + o) * 20 + p] = src[(size_t)(row0 + p) * 64 + o];
  }
  __syncthreads();

  const int o0 = tid, o1 = 256 + tid;
  float S0 = bn7[o0] * rsqrtf(bn7[3*512 + o0] + EPSf);
  float Bs0 = gb7[b*512 + o0] * S0 + bn7[512 + o0] - bn7[2*512 + o0] * S0;
  float S1 = bn7[o1] * rsqrtf(bn7[3*512 + o1] + EPSf);
  float Bs1 = gb7[b*512 + o1] * S1 + bn7[512 + o1] - bn7[2*512 + o1] * S1;
  float acc0[16], acc1[16];
#pragma unroll
  for (int p = 0; p < 16; ++p){ acc0[p] = 0.f; acc1[p] = 0.f; }
#pragma unroll 2
  for (int j = 0; j < 192; ++j){
    float w0 = w7xt[j * 512 + o0];
    float w1 = w7xt[j * 512 + o1];
#pragma unroll
    for (int q = 0; q < 4; ++q){
      float4 f = *(float4*)&A[j * 20 + 4*q];
      acc0[4*q+0] += w0 * f.x; acc0[4*q+1] += w0 * f.y; acc0[4*q+2] += w0 * f.z; acc0[4*q+3] += w0 * f.w;
      acc1[4*q+0] += w1 * f.x; acc1[4*q+1] += w1 * f.y; acc1[4*q+2] += w1 * f.z; acc1[4*q+3] += w1 * f.w;
    }
  }
#pragma unroll
  for (int p = 0; p < 16; ++p){
    H7[o0 * 20 + p] = lrelu(acc0[p] * S0 + Bs0);
    H7[o1 * 20 + p] = lrelu(acc1[p] * S1 + Bs1);
  }
  __syncthreads();

  float S8 = bn8[tid] * rsqrtf(bn8[3*256 + tid] + EPSf);
  float B8 = bn8[256 + tid] - bn8[2*256 + tid] * S8;
  float acc8[16];
#pragma unroll
  for (int p = 0; p < 16; ++p) acc8[p] = 0.f;
#pragma unroll 2
  for (int j = 0; j < 512; ++j){
    float wv = w8t[j * 256 + tid];
#pragma unroll
    for (int q = 0; q < 4; ++q){
      float4 h = *(float4*)&H7[j * 20 + 4*q];
      acc8[4*q+0] += wv * h.x; acc8[4*q+1] += wv * h.y; acc8[4*q+2] += wv * h.z; acc8[4*q+3] += wv * h.w;
    }
  }
  __syncthreads();
#pragma unroll
  for (int p = 0; p < 16; ++p) A[tid * 20 + p] = lrelu(acc8[p] * S8 + B8);
  __syncthreads();

  if (tid < 192){
    int c = tid >> 6, j0 = tid & 63;
    float w9r[4];
#pragma unroll
    for (int q = 0; q < 4; ++q) w9r[q] = W9[c * 256 + j0 + 64*q];
#pragma unroll 1
    for (int p = 0; p < 16; ++p){
      float s = 0.f;
#pragma unroll
      for (int q = 0; q < 4; ++q) s += w9r[q] * A[(j0 + 64*q) * 20 + p];
#pragma unroll
      for (int off = 32; off; off >>= 1) s += __shfl_down(s, off, 64);
      if (j0 == 0) out[(size_t)(row0 + p) * 3 + c] = s;
    }
  }
}

__global__ void sentinel_k(float* __restrict__ o, float val){
  int i = blockIdx.x*256 + threadIdx.x;
  if (i < 106496) o[i] = val;
}

extern "C" void kernel_launch(void* const* d_in, const int* in_sizes, int n_in,
                              void* d_out, int out_size, void* d_ws, size_t ws_size,
                              hipStream_t stream) {
  const float* x  = (const float*)d_in[0];
  const float* W1 = (const float*)d_in[1];
  const float* W2 = (const float*)d_in[2];
  const float* W3 = (const float*)d_in[3];
  const float* W4 = (const float*)d_in[4];
  const float* W5 = (const float*)d_in[5];
  const float* W6 = (const float*)d_in[6];
  const float* W7 = (const float*)d_in[7];
  const float* W8 = (const float*)d_in[8];
  const float* W9 = (const float*)d_in[9];
  const float* bn1 = (const float*)d_in[10];
  const float* bn2 = (const float*)d_in[11];
  const float* bn3 = (const float*)d_in[12];
  const float* bn4 = (const float*)d_in[13];
  const float* bn5 = (const float*)d_in[14];
  const float* bn6 = (const float*)d_in[15];
  const float* bn7 = (const float*)d_in[16];
  const float* bn8 = (const float*)d_in[17];

  float* out_g = (float*)d_out;        // g: 8*1024 fp32
  float* out_o = out_g + 8192;         // out: 8*4096*3 fp32

  bool ok_sizes = (n_in == 18) && in_sizes[0]==98304 && out_size == 106496;
  if (!ok_sizes){ sentinel_k<<<416, 256, 0, stream>>>((float*)d_out, 999.0f); return; }

  float* wsf  = (float*)d_ws;
  float* x1   = wsf;                        // 2,097,152 f
  float* x2   = x1 + 2097152;               // 2,097,152 f
  float* x3   = x2 + 2097152;               // 2,097,152 f
  float* gbuf = x3 + 2097152;               // 8,192 f
  int*   idxb = (int*)(gbuf + 8192);        // 655,360 i
  float* gb7  = (float*)idxb;               // overlay after edge_last
  float* w7xt = gb7 + 4096;
  float* w8t  = w7xt + 98304;
  const size_t NEED = (size_t)(2097152*3 + 8192 + 655360) * 4;
  if (ws_size < NEED){ sentinel_k<<<416, 256, 0, stream>>>((float*)d_out, 12345.0f); return; }

  hipMemsetAsync(gbuf, 0, 8192 * sizeof(float), stream);

  knn1_t<<<256, 128, 0, stream>>>(x, idxb);
  edge_first<<<1024, 256, 0, stream>>>(x, idxb, W1, bn1, W2, bn2, x1);
  knn64_s<<<512, 256, 0, stream>>>(x1, idxb);
  edge_mid<<<1024, 256, 0, stream>>>(x1, idxb, W3, bn3, W4, bn4, x2);
  knn64_s<<<512, 256, 0, stream>>>(x2, idxb);
  edge_last<<<1024, 256, 0, stream>>>(x2, idxb, W5, bn5, x3);
  transpose_k<<<896, 256, 0, stream>>>(W7, W8, w7xt, w8t);
  vf_mean<<<512, 256, 0, stream>>>(x1, x2, x3, W6, bn6, gbuf);
  g_final<<<32, 256, 0, stream>>>(gbuf, out_g);
  gbias7_k<<<16, 256, 0, stream>>>(gbuf, W7, gb7);
  mlp_final<<<2048, 256, 0, stream>>>(x1, x2, x3, w7xt, gb7, bn7, w8t, bn8, W9, out_o);
}